// Round 1
// baseline (10031.208 us; speedup 1.0000x reference)
//
#include <hip/hip_runtime.h>
#include <stdint.h>

#define BB 32
#define TT 2048
#define DD 256
#define GG 1024
#define NWG 32
#define HC 8

typedef __attribute__((ext_vector_type(4))) float f32x4;
typedef __attribute__((ext_vector_type(8))) short s16x8;

static __device__ __forceinline__ unsigned short f2bf(float f) {
    union { float f; unsigned u; } v; v.f = f;
    unsigned r = (v.u + 0x7fffu + ((v.u >> 16) & 1u)) >> 16;
    return (unsigned short)r;
}
static __device__ __forceinline__ float bf2f(unsigned short b) {
    union { unsigned u; float f; } v; v.u = ((unsigned)b) << 16;
    return v.f;
}
static __device__ __forceinline__ float sigm(float x) {
    return 1.0f / (1.0f + __expf(-x));
}
static __device__ __forceinline__ float tanh_f(float x) {
    x = fminf(15.0f, fmaxf(-15.0f, x));
    float e = __expf(2.0f * x);
    return (e - 1.0f) / (e + 1.0f);
}

// Re-zero flags and the t=0 h slots every launch (graph replay safety).
__global__ void k_init(unsigned* __restrict__ h0s0, unsigned* __restrict__ h1s0,
                       unsigned* __restrict__ flags) {
    int i = blockIdx.x * 256 + threadIdx.x;
    if (i < 4096) { h0s0[i] = 0u; h1s0[i] = 0u; }
    if (i < 64) flags[i] = 0u;
}

// 64 WGs: wg 0..31 = layer 0 (owns h-cols [8w,8w+8)), wg 32..63 = layer 1.
// Per step: z[32 x 32cols] = [x_t ; h_prev](32x512) @ Bregs(512x32), gates, publish h slice.
__launch_bounds__(256)
__global__ void k_scan(const float* __restrict__ x,
                       const float* __restrict__ Wi0, const float* __restrict__ Wh0,
                       const float* __restrict__ b0,
                       const float* __restrict__ Wi1, const float* __restrict__ Wh1,
                       const float* __restrict__ b1,
                       unsigned long long* h0buf, unsigned long long* h1buf,
                       unsigned* flags)
{
    const int tid = threadIdx.x;
    const int wgid = blockIdx.x;
    const bool L0 = (wgid < NWG);
    const int w = L0 ? wgid : (wgid - NWG);

    const float* Wi = L0 ? Wi0 : Wi1;
    const float* Wh = L0 ? Wh0 : Wh1;
    const float* bias = L0 ? b0 : b1;

    __shared__ __align__(16) unsigned char Ap[32 * 1024];   // A panel: [32 rows][512 k] bf16, XOR-swizzled
    __shared__ float zbuf[32 * 33];
    __shared__ unsigned short hstage[32 * 8];

    const int lane = tid & 63;
    const int wid = tid >> 6;      // 4 waves
    const int mt = wid & 1;        // M-tile (batch 16)
    const int nt = wid >> 1;       // N-tile (16 gate cols)

    // ---- one-time: weights into registers as MFMA B-fragments ----
    s16x8 Bfrag[16];
    {
        const int jloc = lane & 15;
        const int lcol = nt * 16 + jloc;          // 0..31 local col: [i0-7 f0-7 | g0-7 o0-7]
        const int gate = lcol >> 3;
        const int jj = lcol & 7;
        const int gcol = gate * 256 + w * HC + jj;
        const int krow = (lane >> 4) * 8;
#pragma unroll
        for (int kf = 0; kf < 16; ++kf) {
            s16x8 bfv;
#pragma unroll
            for (int j = 0; j < 8; ++j) {
                int k = kf * 32 + krow + j;
                float wv = (k < 256) ? Wi[(size_t)k * GG + gcol]
                                     : Wh[(size_t)(k - 256) * GG + gcol];
                bfv[j] = (short)f2bf(wv);
            }
            Bfrag[kf] = bfv;
        }
    }

    // gate-update role: thread -> (batch gm, h-col gj)
    const int gm = tid >> 3;
    const int gj = tid & 7;
    const float bi_ = bias[0 * 256 + w * HC + gj];
    const float bf_ = bias[1 * 256 + w * HC + gj];
    const float bg_ = bias[2 * 256 + w * HC + gj];
    const float bo_ = bias[3 * 256 + w * HC + gj];

    // staging role: thread -> (row sr, chunk group sc)
    const int sr = tid >> 3;
    const int sc = tid & 7;
    const unsigned swz = (unsigned)((sr & 7) << 4);

    float c_state = 0.0f;
    long long budget = 20000000LL;   // anti-hang bound; untouched in normal runs

    for (int t = 0; t < TT; ++t) {
        // ---- stage x half (layer 0; no dependency — overlaps flag latency) ----
        if (L0) {
            const float* xs = x + (size_t)sr * (TT * DD) + (size_t)t * DD + sc * 32;
#pragma unroll
            for (int jc = 0; jc < 4; ++jc) {
                float4 va = ((const float4*)xs)[jc * 2 + 0];
                float4 vb = ((const float4*)xs)[jc * 2 + 1];
                uint4 pk;
                pk.x = (unsigned)f2bf(va.x) | ((unsigned)f2bf(va.y) << 16);
                pk.y = (unsigned)f2bf(va.z) | ((unsigned)f2bf(va.w) << 16);
                pk.z = (unsigned)f2bf(vb.x) | ((unsigned)f2bf(vb.y) << 16);
                pk.w = (unsigned)f2bf(vb.z) | ((unsigned)f2bf(vb.w) << 16);
                unsigned byteoff = (unsigned)sr * 1024u + ((((unsigned)(sc * 4 + jc)) * 16u) ^ swz);
                *(uint4*)(Ap + byteoff) = pk;
            }
        }
        // ---- poll seqno flags (agent scope; LLC-coherent) ----
        if (tid < 32) {
            unsigned tgt = L0 ? (unsigned)t : (unsigned)(t + 1);   // L1 needs h0[t+1] ready
            while (__hip_atomic_load(&flags[tid], __ATOMIC_ACQUIRE, __HIP_MEMORY_SCOPE_AGENT) < tgt) {
                if (--budget <= 0) break;
                __builtin_amdgcn_s_sleep(2);
            }
        } else if (!L0 && tid < 64) {
            while (__hip_atomic_load(&flags[tid], __ATOMIC_ACQUIRE, __HIP_MEMORY_SCOPE_AGENT) < (unsigned)t) {
                if (--budget <= 0) break;
                __builtin_amdgcn_s_sleep(2);
            }
        }
        __syncthreads();

        // ---- stage h halves from LLC (agent-scope loads bypass stale L2) ----
        {
            auto stage_half = [&](const unsigned long long* buf, int slot, int half) {
                const unsigned long long* src = buf + (size_t)slot * 2048 + (size_t)sr * 64 + (size_t)sc * 8;
                unsigned long long g[8];
#pragma unroll
                for (int i = 0; i < 8; ++i)
                    g[i] = __hip_atomic_load((unsigned long long*)(src + i),
                                             __ATOMIC_RELAXED, __HIP_MEMORY_SCOPE_AGENT);
#pragma unroll
                for (int jc = 0; jc < 4; ++jc) {
                    uint4 pk;
                    pk.x = (unsigned)(g[2 * jc] & 0xffffffffull);
                    pk.y = (unsigned)(g[2 * jc] >> 32);
                    pk.z = (unsigned)(g[2 * jc + 1] & 0xffffffffull);
                    pk.w = (unsigned)(g[2 * jc + 1] >> 32);
                    unsigned c16 = (unsigned)(half * 32 + sc * 4 + jc);
                    unsigned byteoff = (unsigned)sr * 1024u + ((c16 * 16u) ^ swz);
                    *(uint4*)(Ap + byteoff) = pk;
                }
            };
            if (L0) {
                stage_half(h0buf, t, 1);
            } else {
                stage_half(h0buf, t + 1, 0);   // layer-1 "x" = layer-0 output at step t
                stage_half(h1buf, t, 1);
            }
        }
        __syncthreads();

        // ---- MFMA: z-tile = A(16x512) x B(512x16), B in registers ----
        f32x4 acc = {0.f, 0.f, 0.f, 0.f};
        {
            const unsigned arow = (unsigned)(mt * 16 + (lane & 15));
            const unsigned rbase = arow * 1024u;
            const unsigned asw = (arow & 7u) << 4;
#pragma unroll
            for (int kf = 0; kf < 16; ++kf) {
                unsigned kb = (unsigned)kf * 64u + ((unsigned)(lane >> 4)) * 16u;
                s16x8 a = *(const s16x8*)(Ap + rbase + (kb ^ asw));
                acc = __builtin_amdgcn_mfma_f32_16x16x32_bf16(a, Bfrag[kf], acc, 0, 0, 0);
            }
        }
        // C layout: col = lane&15, row = (lane>>4)*4 + r  [m89-verified]
        {
            const int j = lane & 15;
#pragma unroll
            for (int r = 0; r < 4; ++r) {
                int row = mt * 16 + (lane >> 4) * 4 + r;
                zbuf[row * 33 + nt * 16 + j] = acc[r];
            }
        }
        __syncthreads();

        // ---- gates (fp32, c in register) ----
        {
            float zi = zbuf[gm * 33 + 0  + gj] + bi_;
            float zf = zbuf[gm * 33 + 8  + gj] + bf_;
            float zg = zbuf[gm * 33 + 16 + gj] + bg_;
            float zo = zbuf[gm * 33 + 24 + gj] + bo_;
            c_state = sigm(zf) * c_state + sigm(zi) * tanh_f(zg);
            float h = sigm(zo) * tanh_f(c_state);
            hstage[gm * 8 + gj] = f2bf(h);
        }
        __syncthreads();

        // ---- publish h slice (agent-scope stores -> LLC) ----
        if (tid < 128) {
            int m = tid >> 2, cu = tid & 3;
            unsigned val = ((const unsigned*)hstage)[m * 4 + cu];
            unsigned* dst = (unsigned*)(L0 ? h0buf : h1buf)
                          + (size_t)(t + 1) * 4096 + (size_t)m * 128 + (size_t)(w * 4 + cu);
            __hip_atomic_store(dst, val, __ATOMIC_RELAXED, __HIP_MEMORY_SCOPE_AGENT);
        }
        __syncthreads();   // all slice stores drained (vmcnt(0) before barrier)
        if (tid == 0) {
            __hip_atomic_store(&flags[(L0 ? 0 : NWG) + w], (unsigned)(t + 1),
                               __ATOMIC_RELEASE, __HIP_MEMORY_SCOPE_AGENT);
        }
    }
}

// out = h1[T] @ Wd + bd   (32x256 @ 256x256, fp32)
__global__ void k_dense(const unsigned short* __restrict__ h1last,
                        const float* __restrict__ Wd, const float* __restrict__ bd,
                        float* __restrict__ out)
{
    __shared__ float hs[256];
    const int m = blockIdx.x;
    const int o = threadIdx.x;
    hs[o] = bf2f(h1last[m * 256 + o]);
    __syncthreads();
    float acc = bd[o];
#pragma unroll 8
    for (int k = 0; k < 256; ++k)
        acc = fmaf(hs[k], Wd[k * 256 + o], acc);
    out[m * 256 + o] = acc;
}

extern "C" void kernel_launch(void* const* d_in, const int* in_sizes, int n_in,
                              void* d_out, int out_size, void* d_ws, size_t ws_size,
                              hipStream_t stream)
{
    const float* x   = (const float*)d_in[0];
    const float* Wi0 = (const float*)d_in[1];
    const float* Wh0 = (const float*)d_in[2];
    const float* b0  = (const float*)d_in[3];
    const float* Wi1 = (const float*)d_in[4];
    const float* Wh1 = (const float*)d_in[5];
    const float* b1  = (const float*)d_in[6];
    const float* Wd  = (const float*)d_in[7];
    const float* bd  = (const float*)d_in[8];
    float* out = (float*)d_out;

    char* ws = (char*)d_ws;
    const size_t hbytes = (size_t)(TT + 1) * 16384;            // (T+1) slots x 32x256 bf16
    unsigned long long* h0buf = (unsigned long long*)ws;
    unsigned long long* h1buf = (unsigned long long*)(ws + hbytes);
    unsigned* flags = (unsigned*)(ws + 2 * hbytes);

    k_init<<<dim3(16), dim3(256), 0, stream>>>((unsigned*)h0buf, (unsigned*)h1buf, flags);
    k_scan<<<dim3(64), dim3(256), 0, stream>>>(x, Wi0, Wh0, b0, Wi1, Wh1, b1,
                                               h0buf, h1buf, flags);
    k_dense<<<dim3(32), dim3(256), 0, stream>>>(
        (const unsigned short*)h1buf + (size_t)TT * 8192, Wd, bd, out);
}